// Round 1
// baseline (3576.418 us; speedup 1.0000x reference)
//
#include <hip/hip_runtime.h>
#include <math.h>

#define NEG_SLOPE 0.2f

__device__ __forceinline__ float lrelu(float v) {
    return v > 0.0f ? v : NEG_SLOPE * v;
}

// ---------------- Layer 1 node pass: h1 = x@W1, a_s1/a_d1, zero accumulators
__global__ __launch_bounds__(256) void k_l1_node(
    const float* __restrict__ x, const float* __restrict__ W1,
    const float* __restrict__ asw, const float* __restrict__ adw,
    float* __restrict__ h1, float* __restrict__ a_s1, float* __restrict__ a_d1,
    float* __restrict__ s1, float* __restrict__ acc1, int n)
{
    int i = blockIdx.x * blockDim.x + threadIdx.x;
    if (i >= n) return;
    float x0 = x[2 * i], x1 = x[2 * i + 1];
    float as[4] = {0.f, 0.f, 0.f, 0.f};
    float ad[4] = {0.f, 0.f, 0.f, 0.f};
    float* h1p = h1 + (size_t)i * 32;
    float4* accv = (float4*)(acc1 + (size_t)i * 32);
    #pragma unroll
    for (int j = 0; j < 32; ++j) {
        float h = x0 * W1[j] + x1 * W1[32 + j];
        h1p[j] = h;
        as[j >> 3] += h * asw[j];
        ad[j >> 3] += h * adw[j];
    }
    float4 z = make_float4(0.f, 0.f, 0.f, 0.f);
    #pragma unroll
    for (int q = 0; q < 8; ++q) accv[q] = z;
    *(float4*)(a_s1 + 4 * (size_t)i) = make_float4(as[0], as[1], as[2], as[3]);
    *(float4*)(a_d1 + 4 * (size_t)i) = make_float4(ad[0], ad[1], ad[2], ad[3]);
    *(float4*)(s1 + 4 * (size_t)i) = z;
}

// ---------------- Layer 1 edge pass: 4 threads per edge (one per head).
// Accumulates s1[dst][h] += ee, acc1[dst][h*8+c] += h1[src][h*8+c]*ee
__global__ __launch_bounds__(256) void k_l1_edge(
    const int* __restrict__ ei,
    const float* __restrict__ a_s1, const float* __restrict__ a_d1,
    const float* __restrict__ h1,
    float* __restrict__ s1, float* __restrict__ acc1, int E, int Et)
{
    int t = blockIdx.x * blockDim.x + threadIdx.x;
    int e = t >> 2, h = t & 3;
    if (e >= Et) return;
    int s, d;
    if (e < E) { s = ei[e]; d = ei[E + e]; } else { s = e - E; d = s; }
    float el = lrelu(a_s1[4 * (size_t)s + h] + a_d1[4 * (size_t)d + h]);
    float ee = __expf(el);
    unsafeAtomicAdd(&s1[4 * (size_t)d + h], ee);
    const float4* hv = (const float4*)(h1 + (size_t)s * 32 + h * 8);
    float4 v0 = hv[0], v1 = hv[1];
    float* ac = acc1 + (size_t)d * 32 + h * 8;
    unsafeAtomicAdd(ac + 0, v0.x * ee);
    unsafeAtomicAdd(ac + 1, v0.y * ee);
    unsafeAtomicAdd(ac + 2, v0.z * ee);
    unsafeAtomicAdd(ac + 3, v0.w * ee);
    unsafeAtomicAdd(ac + 4, v1.x * ee);
    unsafeAtomicAdd(ac + 5, v1.y * ee);
    unsafeAtomicAdd(ac + 6, v1.z * ee);
    unsafeAtomicAdd(ac + 7, v1.w * ee);
}

// ---------------- Layer 2 node prep: out1 = acc1/(s1+eps)+b1; h=elu(out1);
// h2 = h@W2; a_s2/a_d2; zero s2/acc2
__global__ __launch_bounds__(256) void k_l2_node(
    const float* __restrict__ acc1, const float* __restrict__ s1,
    const float* __restrict__ b1, const float* __restrict__ W2,
    const float* __restrict__ asw2, const float* __restrict__ adw2,
    float* __restrict__ h2, float* __restrict__ a_s2, float* __restrict__ a_d2,
    float* __restrict__ s2, float* __restrict__ acc2, int n)
{
    int i = blockIdx.x * blockDim.x + threadIdx.x;
    if (i >= n) return;
    float4 sv = *(const float4*)(s1 + 4 * (size_t)i);
    float sdenom[4] = {sv.x + 1e-16f, sv.y + 1e-16f, sv.z + 1e-16f, sv.w + 1e-16f};
    const float* ac = acc1 + (size_t)i * 32;
    float h20 = 0.f, h21 = 0.f;
    #pragma unroll
    for (int j = 0; j < 32; ++j) {
        float o = ac[j] / sdenom[j >> 3] + b1[j];
        float he = o > 0.f ? o : expm1f(o);
        h20 += he * W2[2 * j];
        h21 += he * W2[2 * j + 1];
    }
    *(float2*)(h2 + 2 * (size_t)i) = make_float2(h20, h21);
    a_s2[i] = h20 * asw2[0] + h21 * asw2[1];
    a_d2[i] = h20 * adw2[0] + h21 * adw2[1];
    s2[i] = 0.f;
    *(float2*)(acc2 + 2 * (size_t)i) = make_float2(0.f, 0.f);
}

// ---------------- Fused edge pass: write alpha1 (layer1 normalized) and
// accumulate layer-2 s2/acc2.
__global__ __launch_bounds__(256) void k_mid_edge(
    const int* __restrict__ ei,
    const float* __restrict__ a_s1, const float* __restrict__ a_d1,
    const float* __restrict__ s1,
    const float* __restrict__ a_s2, const float* __restrict__ a_d2,
    const float* __restrict__ h2,
    float* __restrict__ s2, float* __restrict__ acc2,
    float* __restrict__ alpha1, int E, int Et)
{
    int e = blockIdx.x * blockDim.x + threadIdx.x;
    if (e >= Et) return;
    int s, d;
    if (e < E) { s = ei[e]; d = ei[E + e]; } else { s = e - E; d = s; }
    // layer-1 alpha
    float4 as = *(const float4*)(a_s1 + 4 * (size_t)s);
    float4 ad = *(const float4*)(a_d1 + 4 * (size_t)d);
    float4 sv = *(const float4*)(s1 + 4 * (size_t)d);
    float4 al;
    al.x = __expf(lrelu(as.x + ad.x)) / (sv.x + 1e-16f);
    al.y = __expf(lrelu(as.y + ad.y)) / (sv.y + 1e-16f);
    al.z = __expf(lrelu(as.z + ad.z)) / (sv.z + 1e-16f);
    al.w = __expf(lrelu(as.w + ad.w)) / (sv.w + 1e-16f);
    *(float4*)(alpha1 + 4 * (size_t)e) = al;
    // layer-2 accumulate
    float e2 = lrelu(a_s2[s] + a_d2[d]);
    float ee2 = __expf(e2);
    unsafeAtomicAdd(&s2[d], ee2);
    float2 hv = *(const float2*)(h2 + 2 * (size_t)s);
    unsafeAtomicAdd(&acc2[2 * (size_t)d + 0], hv.x * ee2);
    unsafeAtomicAdd(&acc2[2 * (size_t)d + 1], hv.y * ee2);
}

// ---------------- Output node pass
__global__ __launch_bounds__(256) void k_out_node(
    const float* __restrict__ acc2, const float* __restrict__ s2,
    const float* __restrict__ b2, float* __restrict__ out, int n)
{
    int i = blockIdx.x * blockDim.x + threadIdx.x;
    if (i >= n) return;
    float denom = s2[i] + 1e-16f;
    float2 a = *(const float2*)(acc2 + 2 * (size_t)i);
    *(float2*)(out + 2 * (size_t)i) = make_float2(a.x / denom + b2[0], a.y / denom + b2[1]);
}

// ---------------- alpha2 edge pass
__global__ __launch_bounds__(256) void k_alpha2_edge(
    const int* __restrict__ ei,
    const float* __restrict__ a_s2, const float* __restrict__ a_d2,
    const float* __restrict__ s2, float* __restrict__ alpha2, int E, int Et)
{
    int e = blockIdx.x * blockDim.x + threadIdx.x;
    if (e >= Et) return;
    int s, d;
    if (e < E) { s = ei[e]; d = ei[E + e]; } else { s = e - E; d = s; }
    float ee = __expf(lrelu(a_s2[s] + a_d2[d]));
    alpha2[e] = ee / (s2[d] + 1e-16f);
}

extern "C" void kernel_launch(void* const* d_in, const int* in_sizes, int n_in,
                              void* d_out, int out_size, void* d_ws, size_t ws_size,
                              hipStream_t stream)
{
    const float* x   = (const float*)d_in[0];
    const int*   ei  = (const int*)d_in[1];   // [2,E] int32 (src row then dst row)
    // d_in[2] = edge_attr, ignored by reference
    const float* W1  = (const float*)d_in[3];
    const float* as1 = (const float*)d_in[4];
    const float* ad1 = (const float*)d_in[5];
    const float* b1  = (const float*)d_in[6];
    const float* W2  = (const float*)d_in[7];
    const float* as2 = (const float*)d_in[8];
    const float* ad2 = (const float*)d_in[9];
    const float* b2  = (const float*)d_in[10];

    const int n  = in_sizes[0] / 2;   // 100000
    const int E  = in_sizes[1] / 2;   // 3200000
    const int Et = E + n;             // with self loops

    float* ws   = (float*)d_ws;
    float* h1   = ws;                         // n*32
    float* a_s1 = h1 + (size_t)n * 32;        // n*4
    float* a_d1 = a_s1 + (size_t)n * 4;       // n*4
    float* s1   = a_d1 + (size_t)n * 4;       // n*4
    float* acc1 = s1 + (size_t)n * 4;         // n*32
    float* h2   = acc1 + (size_t)n * 32;      // n*2
    float* a_s2 = h2 + (size_t)n * 2;         // n
    float* a_d2 = a_s2 + (size_t)n;           // n
    float* s2   = a_d2 + (size_t)n;           // n
    float* acc2 = s2 + (size_t)n;             // n*2

    float* out    = (float*)d_out;
    float* alpha1 = out + (size_t)n * 2;
    float* alpha2 = alpha1 + (size_t)Et * 4;

    dim3 blk(256);
    int gn = (n + 255) / 256;
    int ge4 = (int)(((long long)Et * 4 + 255) / 256);
    int ge = (Et + 255) / 256;

    k_l1_node<<<gn, blk, 0, stream>>>(x, W1, as1, ad1, h1, a_s1, a_d1, s1, acc1, n);
    k_l1_edge<<<ge4, blk, 0, stream>>>(ei, a_s1, a_d1, h1, s1, acc1, E, Et);
    k_l2_node<<<gn, blk, 0, stream>>>(acc1, s1, b1, W2, as2, ad2, h2, a_s2, a_d2, s2, acc2, n);
    k_mid_edge<<<ge, blk, 0, stream>>>(ei, a_s1, a_d1, s1, a_s2, a_d2, h2, s2, acc2, alpha1, E, Et);
    k_out_node<<<gn, blk, 0, stream>>>(acc2, s2, b2, out, n);
    k_alpha2_edge<<<ge, blk, 0, stream>>>(ei, a_s2, a_d2, s2, alpha2, E, Et);
}

// Round 2
// 818.021 us; speedup vs baseline: 4.3720x; 4.3720x over previous
//
#include <hip/hip_runtime.h>
#include <math.h>

#define NEG_SLOPE 0.2f

__device__ __forceinline__ float lrelu(float v) {
    return v > 0.0f ? v : NEG_SLOPE * v;
}

// ---------------- K1: per-node layer-1 projection + attention dots.
// pk1[i] = {as0,as1,as2,as3} , {x0,x1,0,0}  (two float4)
__global__ __launch_bounds__(256) void k_l1_node(
    const float* __restrict__ x, const float* __restrict__ W1,
    const float* __restrict__ asw, const float* __restrict__ adw,
    float4* __restrict__ pk1, float4* __restrict__ a_d1,
    int* __restrict__ cnt, int n)
{
    int i = blockIdx.x * blockDim.x + threadIdx.x;
    if (i >= n) return;
    float x0 = x[2 * i], x1 = x[2 * i + 1];
    float as[4] = {0.f, 0.f, 0.f, 0.f};
    float ad[4] = {0.f, 0.f, 0.f, 0.f};
    #pragma unroll
    for (int j = 0; j < 32; ++j) {
        float h = x0 * W1[j] + x1 * W1[32 + j];
        as[j >> 3] += h * asw[j];
        ad[j >> 3] += h * adw[j];
    }
    pk1[2 * i]     = make_float4(as[0], as[1], as[2], as[3]);
    pk1[2 * i + 1] = make_float4(x0, x1, 0.f, 0.f);
    a_d1[i]        = make_float4(ad[0], ad[1], ad[2], ad[3]);
    cnt[i] = 1;  // self-loop pre-count
}

// ---------------- K2: degree histogram over dst (int atomics)
__global__ __launch_bounds__(256) void k_hist(
    const int* __restrict__ ei, int* __restrict__ cnt, int E)
{
    int e = blockIdx.x * blockDim.x + threadIdx.x;
    if (e >= E) return;
    atomicAdd(&cnt[ei[E + e]], 1);
}

// ---------------- K3: exclusive scan of cnt -> offs (single block, 1024 thr)
__global__ __launch_bounds__(1024) void k_scan(
    const int* __restrict__ cnt, int* __restrict__ offs, int n)
{
    __shared__ int part[1024];
    const int CH = (n + 1023) / 1024;
    int t = threadIdx.x;
    int beg = t * CH, end = min(beg + CH, n);
    int s = 0;
    for (int i = beg; i < end; ++i) s += cnt[i];
    part[t] = s;
    __syncthreads();
    // Hillis-Steele inclusive scan on part[]
    for (int off = 1; off < 1024; off <<= 1) {
        int v = (t >= off) ? part[t - off] : 0;
        __syncthreads();
        part[t] += v;
        __syncthreads();
    }
    int run = (t > 0) ? part[t - 1] : 0;  // exclusive prefix of this chunk
    for (int i = beg; i < end; ++i) {
        offs[i] = run;
        run += cnt[i];
    }
}

// ---------------- K4: scatter edges into CSR order (src only).
// offs[d] advances to row_end; row_start[d] = (d ? offs[d-1] : 0) afterwards.
__global__ __launch_bounds__(256) void k_scatter(
    const int* __restrict__ ei, int* __restrict__ offs,
    int* __restrict__ sorted, int E, int Et)
{
    int e = blockIdx.x * blockDim.x + threadIdx.x;
    if (e >= Et) return;
    int s, d;
    if (e < E) { s = ei[e]; d = ei[E + e]; } else { s = e - E; d = s; }
    int p = atomicAdd(&offs[d], 1);
    sorted[p] = s;
}

// ---------------- K5: CSR layer-1 gather (1 thread per dst) + layer-2 node prep.
// Accumulates per head: see, sx0 (ee*x0), sx1 (ee*x1) in registers.
// Epilogue expands via W1, applies softmax-normalize + bias + ELU, computes
// h2 = he@W2 and attention dots; pk2[d] = {a_s2, h2x, h2y, a_d2}.
__global__ __launch_bounds__(256) void k_l1_gather(
    const int* __restrict__ offs, const int* __restrict__ sorted,
    const float4* __restrict__ pk1, const float4* __restrict__ a_d1,
    const float* __restrict__ W1, const float* __restrict__ b1,
    const float* __restrict__ W2,
    const float* __restrict__ asw2, const float* __restrict__ adw2,
    float4* __restrict__ s1, float4* __restrict__ pk2, int n)
{
    int d = blockIdx.x * blockDim.x + threadIdx.x;
    if (d >= n) return;
    int beg = (d > 0) ? offs[d - 1] : 0;
    int end = offs[d];
    float4 ad = a_d1[d];
    float see[4] = {0.f, 0.f, 0.f, 0.f};
    float sx0[4] = {0.f, 0.f, 0.f, 0.f};
    float sx1[4] = {0.f, 0.f, 0.f, 0.f};
    int s_next = (beg < end) ? sorted[beg] : 0;
    for (int i = beg; i < end; ++i) {
        int s = s_next;
        if (i + 1 < end) s_next = sorted[i + 1];
        float4 pa = pk1[2 * s];
        float4 pb = pk1[2 * s + 1];
        float e0 = __expf(lrelu(pa.x + ad.x));
        float e1 = __expf(lrelu(pa.y + ad.y));
        float e2 = __expf(lrelu(pa.z + ad.z));
        float e3 = __expf(lrelu(pa.w + ad.w));
        see[0] += e0; sx0[0] += e0 * pb.x; sx1[0] += e0 * pb.y;
        see[1] += e1; sx0[1] += e1 * pb.x; sx1[1] += e1 * pb.y;
        see[2] += e2; sx0[2] += e2 * pb.x; sx1[2] += e2 * pb.y;
        see[3] += e3; sx0[3] += e3 * pb.x; sx1[3] += e3 * pb.y;
    }
    s1[d] = make_float4(see[0], see[1], see[2], see[3]);
    float h20 = 0.f, h21 = 0.f;
    #pragma unroll
    for (int j = 0; j < 32; ++j) {
        int h = j >> 3;
        float num = W1[j] * sx0[h] + W1[32 + j] * sx1[h];
        float o = num / (see[h] + 1e-16f) + b1[j];
        float he = o > 0.f ? o : expm1f(o);
        h20 += he * W2[2 * j];
        h21 += he * W2[2 * j + 1];
    }
    float as2 = h20 * asw2[0] + h21 * asw2[1];
    float ad2 = h20 * adw2[0] + h21 * adw2[1];
    pk2[d] = make_float4(as2, h20, h21, ad2);
}

// ---------------- K6: CSR layer-2 gather (1 thread per dst) + output epilogue.
__global__ __launch_bounds__(256) void k_l2_gather(
    const int* __restrict__ offs, const int* __restrict__ sorted,
    const float4* __restrict__ pk2, const float* __restrict__ b2,
    float* __restrict__ s2, float* __restrict__ out, int n)
{
    int d = blockIdx.x * blockDim.x + threadIdx.x;
    if (d >= n) return;
    int beg = (d > 0) ? offs[d - 1] : 0;
    int end = offs[d];
    float ad2 = pk2[d].w;
    float se = 0.f, a0 = 0.f, a1 = 0.f;
    int s_next = (beg < end) ? sorted[beg] : 0;
    for (int i = beg; i < end; ++i) {
        int s = s_next;
        if (i + 1 < end) s_next = sorted[i + 1];
        float4 p = pk2[s];
        float ee = __expf(lrelu(p.x + ad2));
        se += ee;
        a0 += ee * p.y;
        a1 += ee * p.z;
    }
    s2[d] = se;
    float denom = se + 1e-16f;
    out[2 * d]     = a0 / denom + b2[0];
    out[2 * d + 1] = a1 / denom + b2[1];
}

// ---------------- K7: COO pass writing alpha1 [Et,4] and alpha2 [Et].
__global__ __launch_bounds__(256) void k_alpha(
    const int* __restrict__ ei,
    const float4* __restrict__ pk1, const float4* __restrict__ a_d1,
    const float4* __restrict__ s1, const float4* __restrict__ pk2,
    const float* __restrict__ s2,
    float4* __restrict__ alpha1, float* __restrict__ alpha2, int E, int Et)
{
    int e = blockIdx.x * blockDim.x + threadIdx.x;
    if (e >= Et) return;
    int s, d;
    if (e < E) { s = ei[e]; d = ei[E + e]; } else { s = e - E; d = s; }
    float4 as = pk1[2 * s];
    float4 ad = a_d1[d];
    float4 sv = s1[d];
    float4 al;
    al.x = __expf(lrelu(as.x + ad.x)) / (sv.x + 1e-16f);
    al.y = __expf(lrelu(as.y + ad.y)) / (sv.y + 1e-16f);
    al.z = __expf(lrelu(as.z + ad.z)) / (sv.z + 1e-16f);
    al.w = __expf(lrelu(as.w + ad.w)) / (sv.w + 1e-16f);
    alpha1[e] = al;
    float e2 = __expf(lrelu(pk2[s].x + pk2[d].w));
    alpha2[e] = e2 / (s2[d] + 1e-16f);
}

extern "C" void kernel_launch(void* const* d_in, const int* in_sizes, int n_in,
                              void* d_out, int out_size, void* d_ws, size_t ws_size,
                              hipStream_t stream)
{
    const float* x   = (const float*)d_in[0];
    const int*   ei  = (const int*)d_in[1];   // [2,E] int (src row then dst row)
    const float* W1  = (const float*)d_in[3];
    const float* as1 = (const float*)d_in[4];
    const float* ad1 = (const float*)d_in[5];
    const float* b1  = (const float*)d_in[6];
    const float* W2  = (const float*)d_in[7];
    const float* as2 = (const float*)d_in[8];
    const float* ad2 = (const float*)d_in[9];
    const float* b2  = (const float*)d_in[10];

    const int n  = in_sizes[0] / 2;   // 100000
    const int E  = in_sizes[1] / 2;   // 3200000
    const int Et = E + n;

    char* w = (char*)d_ws;
    float4* pk1  = (float4*)w;                 w += (size_t)n * 2 * sizeof(float4);
    float4* a_d1v= (float4*)w;                 w += (size_t)n * sizeof(float4);
    float4* s1   = (float4*)w;                 w += (size_t)n * sizeof(float4);
    float4* pk2  = (float4*)w;                 w += (size_t)n * sizeof(float4);
    float*  s2   = (float*)w;                  w += (size_t)n * sizeof(float);
    int*    cnt  = (int*)w;                    w += (size_t)n * sizeof(int);
    int*    offs = (int*)w;                    w += (size_t)n * sizeof(int);
    int*    sorted = (int*)w;                  w += (size_t)Et * sizeof(int);

    float*  out    = (float*)d_out;
    float4* alpha1 = (float4*)(out + (size_t)n * 2);
    float*  alpha2 = (float*)(alpha1 + (size_t)Et);

    dim3 blk(256);
    int gn  = (n + 255) / 256;
    int gE  = (E + 255) / 256;
    int gEt = (Et + 255) / 256;

    k_l1_node  <<<gn,  blk, 0, stream>>>(x, W1, as1, ad1, pk1, a_d1v, cnt, n);
    k_hist     <<<gE,  blk, 0, stream>>>(ei, cnt, E);
    k_scan     <<<1, dim3(1024), 0, stream>>>(cnt, offs, n);
    k_scatter  <<<gEt, blk, 0, stream>>>(ei, offs, sorted, E, Et);
    k_l1_gather<<<gn,  blk, 0, stream>>>(offs, sorted, pk1, a_d1v, W1, b1, W2,
                                         as2, ad2, s1, pk2, n);
    k_l2_gather<<<gn,  blk, 0, stream>>>(offs, sorted, pk2, b2, s2, out, n);
    k_alpha    <<<gEt, blk, 0, stream>>>(ei, pk1, a_d1v, s1, pk2, s2,
                                         alpha1, alpha2, E, Et);
}

// Round 3
// 418.723 us; speedup vs baseline: 8.5413x; 1.9536x over previous
//
#include <hip/hip_runtime.h>
#include <math.h>

#define NEG_SLOPE 0.2f
#define BW 512          // bucket node width
#define BSH 9           // log2(BW)
#define CAP 18432       // per-bucket edge capacity (mean ~16.9K, +12 sigma)
#define NB_MAX 256      // static LDS sizing for bucket arrays

__device__ __forceinline__ float lrelu(float v) {
    return v > 0.0f ? v : NEG_SLOPE * v;
}

// ---------------- K1: per-node layer-1 projection + attention dots.
// pk1[i] = {as0,as1,as2,as3} , {x0,x1,0,0}
__global__ __launch_bounds__(256) void k_l1_node(
    const float* __restrict__ x, const float* __restrict__ W1,
    const float* __restrict__ asw, const float* __restrict__ adw,
    float4* __restrict__ pk1, float4* __restrict__ a_d1, int n)
{
    int i = blockIdx.x * blockDim.x + threadIdx.x;
    if (i >= n) return;
    float x0 = x[2 * i], x1 = x[2 * i + 1];
    float as[4] = {0.f, 0.f, 0.f, 0.f};
    float ad[4] = {0.f, 0.f, 0.f, 0.f};
    #pragma unroll
    for (int j = 0; j < 32; ++j) {
        float h = x0 * W1[j] + x1 * W1[32 + j];
        as[j >> 3] += h * asw[j];
        ad[j >> 3] += h * adw[j];
    }
    pk1[2 * i]     = make_float4(as[0], as[1], as[2], as[3]);
    pk1[2 * i + 1] = make_float4(x0, x1, 0.f, 0.f);
    a_d1[i]        = make_float4(ad[0], ad[1], ad[2], ad[3]);
}

// ---------------- K0: zero bucket cursors
__global__ __launch_bounds__(256) void k_init(int* __restrict__ bucketCursor, int nb)
{
    int t = blockIdx.x * blockDim.x + threadIdx.x;
    if (t < nb) bucketCursor[t] = 0;
}

// ---------------- KA: LDS-binned bucket scatter (chunk=4096 edges/block).
// Bins edges by dst bucket (b = d>>9) into LDS staging, then writes each
// bucket's run contiguously to binned[b*CAP + cursor...] (coalesced bursts).
__global__ __launch_bounds__(256) void k_binA(
    const int* __restrict__ ei, int* __restrict__ bucketCursor,
    unsigned int* __restrict__ binned, int E, int Et, int nb)
{
    __shared__ int cnt[NB_MAX], lscan[NB_MAX + 1], base[NB_MAX], lcur[NB_MAX];
    __shared__ unsigned int staging[4096];
    int t = threadIdx.x;
    int c0 = blockIdx.x * 4096;
    unsigned int ent[16];
    short bb[16];
    #pragma unroll
    for (int k = 0; k < 16; ++k) {
        int e = c0 + k * 256 + t;
        int s, d;
        if (e < E) { s = ei[e]; d = ei[E + e]; }
        else       { s = e - E; d = s; }
        bool valid = e < Et;
        bb[k] = valid ? (short)(d >> BSH) : (short)(-1);
        ent[k] = ((unsigned int)s << BSH) | (unsigned int)(d & (BW - 1));
    }
    if (t < nb) cnt[t] = 0;
    __syncthreads();
    #pragma unroll
    for (int k = 0; k < 16; ++k)
        if (bb[k] >= 0) atomicAdd(&cnt[bb[k]], 1);
    __syncthreads();
    if (t == 0) {
        int r = 0;
        for (int b = 0; b < nb; ++b) { lscan[b] = r; r += cnt[b]; }
        lscan[nb] = r;
    }
    __syncthreads();
    if (t < nb) {
        if (cnt[t] > 0) base[t] = atomicAdd(&bucketCursor[t], cnt[t]);
        lcur[t] = lscan[t];
    }
    __syncthreads();
    #pragma unroll
    for (int k = 0; k < 16; ++k)
        if (bb[k] >= 0) {
            int p = atomicAdd(&lcur[bb[k]], 1);
            staging[p] = ent[k];
        }
    __syncthreads();
    int total = lscan[nb];
    for (int j = t; j < total; j += 256) {
        int lo = 0, hi = nb - 1;
        while (lo < hi) {
            int mid = (lo + hi + 1) >> 1;
            if (lscan[mid] <= j) lo = mid; else hi = mid - 1;
        }
        binned[(size_t)lo * CAP + base[lo] + (j - lscan[lo])] = staging[j];
    }
}

// ---------------- KB: per-bucket counting sort -> CSR (no global atomics).
// One block per bucket, 512 threads (one per local node).
__global__ __launch_bounds__(512) void k_binB(
    const unsigned int* __restrict__ binned, const int* __restrict__ bucketCursor,
    int* __restrict__ sorted, int2* __restrict__ rowrange, int n, int nb)
{
    __shared__ int cnt[BW], cur[BW];
    int t = threadIdx.x;
    int b = blockIdx.x;
    int m = bucketCursor[b];
    size_t base = (size_t)b * CAP;
    int node0 = b << BSH;
    cnt[t] = 0;
    __syncthreads();
    for (int i = t; i < m; i += BW)
        atomicAdd(&cnt[binned[base + i] & (BW - 1)], 1);
    __syncthreads();
    int deg = cnt[t];
    // inclusive Hillis-Steele scan over BW entries
    for (int off = 1; off < BW; off <<= 1) {
        int v = (t >= off) ? cnt[t - off] : 0;
        __syncthreads();
        cnt[t] += v;
        __syncthreads();
    }
    int ex = cnt[t] - deg;
    cur[t] = ex;
    int node = node0 + t;
    if (node < n)
        rowrange[node] = make_int2((int)base + ex, (int)base + ex + deg);
    __syncthreads();
    for (int i = t; i < m; i += BW) {
        unsigned int en = binned[base + i];
        int dl = (int)(en & (BW - 1));
        int p = atomicAdd(&cur[dl], 1);
        sorted[base + p] = (int)(en >> BSH);
    }
}

// ---------------- K5: CSR layer-1 gather (1 thread/dst) + layer-2 node prep.
__global__ __launch_bounds__(256) void k_l1_gather(
    const int2* __restrict__ rowrange, const int* __restrict__ sorted,
    const float4* __restrict__ pk1, const float4* __restrict__ a_d1,
    const float* __restrict__ W1, const float* __restrict__ b1,
    const float* __restrict__ W2,
    const float* __restrict__ asw2, const float* __restrict__ adw2,
    float4* __restrict__ s1, float4* __restrict__ pk2, int n)
{
    int d = blockIdx.x * blockDim.x + threadIdx.x;
    if (d >= n) return;
    int2 rr = rowrange[d];
    int beg = rr.x, end = rr.y;
    float4 ad = a_d1[d];
    float see[4] = {0.f, 0.f, 0.f, 0.f};
    float sx0[4] = {0.f, 0.f, 0.f, 0.f};
    float sx1[4] = {0.f, 0.f, 0.f, 0.f};
    int s_next = (beg < end) ? sorted[beg] : 0;
    for (int i = beg; i < end; ++i) {
        int s = s_next;
        if (i + 1 < end) s_next = sorted[i + 1];
        float4 pa = pk1[2 * s];
        float4 pb = pk1[2 * s + 1];
        float e0 = __expf(lrelu(pa.x + ad.x));
        float e1 = __expf(lrelu(pa.y + ad.y));
        float e2 = __expf(lrelu(pa.z + ad.z));
        float e3 = __expf(lrelu(pa.w + ad.w));
        see[0] += e0; sx0[0] += e0 * pb.x; sx1[0] += e0 * pb.y;
        see[1] += e1; sx0[1] += e1 * pb.x; sx1[1] += e1 * pb.y;
        see[2] += e2; sx0[2] += e2 * pb.x; sx1[2] += e2 * pb.y;
        see[3] += e3; sx0[3] += e3 * pb.x; sx1[3] += e3 * pb.y;
    }
    s1[d] = make_float4(see[0], see[1], see[2], see[3]);
    float h20 = 0.f, h21 = 0.f;
    #pragma unroll
    for (int j = 0; j < 32; ++j) {
        int h = j >> 3;
        float num = W1[j] * sx0[h] + W1[32 + j] * sx1[h];
        float o = num / (see[h] + 1e-16f) + b1[j];
        float he = o > 0.f ? o : expm1f(o);
        h20 += he * W2[2 * j];
        h21 += he * W2[2 * j + 1];
    }
    float as2 = h20 * asw2[0] + h21 * asw2[1];
    float ad2 = h20 * adw2[0] + h21 * adw2[1];
    pk2[d] = make_float4(as2, h20, h21, ad2);
}

// ---------------- K6: CSR layer-2 gather (1 thread/dst) + output epilogue.
__global__ __launch_bounds__(256) void k_l2_gather(
    const int2* __restrict__ rowrange, const int* __restrict__ sorted,
    const float4* __restrict__ pk2, const float* __restrict__ b2,
    float* __restrict__ s2, float* __restrict__ out, int n)
{
    int d = blockIdx.x * blockDim.x + threadIdx.x;
    if (d >= n) return;
    int2 rr = rowrange[d];
    int beg = rr.x, end = rr.y;
    float ad2 = pk2[d].w;
    float se = 0.f, a0 = 0.f, a1 = 0.f;
    int s_next = (beg < end) ? sorted[beg] : 0;
    for (int i = beg; i < end; ++i) {
        int s = s_next;
        if (i + 1 < end) s_next = sorted[i + 1];
        float4 p = pk2[s];
        float ee = __expf(lrelu(p.x + ad2));
        se += ee;
        a0 += ee * p.y;
        a1 += ee * p.z;
    }
    s2[d] = se;
    float denom = se + 1e-16f;
    out[2 * d]     = a0 / denom + b2[0];
    out[2 * d + 1] = a1 / denom + b2[1];
}

// ---------------- K7: COO pass writing alpha1 [Et,4] and alpha2 [Et].
// Runs LAST: overwrites the alpha1 region that k_binA used as scratch.
__global__ __launch_bounds__(256) void k_alpha(
    const int* __restrict__ ei,
    const float4* __restrict__ pk1, const float4* __restrict__ a_d1,
    const float4* __restrict__ s1, const float4* __restrict__ pk2,
    const float* __restrict__ s2,
    float4* __restrict__ alpha1, float* __restrict__ alpha2, int E, int Et)
{
    int e = blockIdx.x * blockDim.x + threadIdx.x;
    if (e >= Et) return;
    int s, d;
    if (e < E) { s = ei[e]; d = ei[E + e]; } else { s = e - E; d = s; }
    float4 as = pk1[2 * s];
    float4 ad = a_d1[d];
    float4 sv = s1[d];
    float4 al;
    al.x = __expf(lrelu(as.x + ad.x)) / (sv.x + 1e-16f);
    al.y = __expf(lrelu(as.y + ad.y)) / (sv.y + 1e-16f);
    al.z = __expf(lrelu(as.z + ad.z)) / (sv.z + 1e-16f);
    al.w = __expf(lrelu(as.w + ad.w)) / (sv.w + 1e-16f);
    alpha1[e] = al;
    float e2 = __expf(lrelu(pk2[s].x + pk2[d].w));
    alpha2[e] = e2 / (s2[d] + 1e-16f);
}

extern "C" void kernel_launch(void* const* d_in, const int* in_sizes, int n_in,
                              void* d_out, int out_size, void* d_ws, size_t ws_size,
                              hipStream_t stream)
{
    const float* x   = (const float*)d_in[0];
    const int*   ei  = (const int*)d_in[1];
    const float* W1  = (const float*)d_in[3];
    const float* as1 = (const float*)d_in[4];
    const float* ad1 = (const float*)d_in[5];
    const float* b1  = (const float*)d_in[6];
    const float* W2  = (const float*)d_in[7];
    const float* as2 = (const float*)d_in[8];
    const float* ad2 = (const float*)d_in[9];
    const float* b2  = (const float*)d_in[10];

    const int n  = in_sizes[0] / 2;   // 100000
    const int E  = in_sizes[1] / 2;   // 3200000
    const int Et = E + n;
    const int nb = (n + BW - 1) >> BSH;  // 196 buckets

    char* w = (char*)d_ws;
    float4* pk1   = (float4*)w;  w += (size_t)n * 2 * sizeof(float4);
    float4* a_d1v = (float4*)w;  w += (size_t)n * sizeof(float4);
    float4* s1    = (float4*)w;  w += (size_t)n * sizeof(float4);
    float4* pk2   = (float4*)w;  w += (size_t)n * sizeof(float4);
    float*  s2    = (float*)w;   w += (size_t)n * sizeof(float);
    int2*   rowrange = (int2*)w; w += (size_t)n * sizeof(int2);
    int*    sorted   = (int*)w;  w += (size_t)nb * CAP * sizeof(int);
    int*    bucketCursor = (int*)w; w += (size_t)nb * sizeof(int);

    float*  out    = (float*)d_out;
    float4* alpha1 = (float4*)(out + (size_t)n * 2);
    float*  alpha2 = (float*)(alpha1 + (size_t)Et);
    // scratch for binned entries: lives in the alpha1 region (14.5MB of 52.8MB),
    // consumed by k_binB, overwritten by k_alpha at the end.
    unsigned int* binned = (unsigned int*)alpha1;

    dim3 blk(256);
    int gn  = (n + 255) / 256;
    int gEt = (Et + 255) / 256;
    int gA  = (Et + 4095) / 4096;

    k_l1_node  <<<gn,  blk, 0, stream>>>(x, W1, as1, ad1, pk1, a_d1v, n);
    k_init     <<<1,   blk, 0, stream>>>(bucketCursor, nb);
    k_binA     <<<gA,  blk, 0, stream>>>(ei, bucketCursor, binned, E, Et, nb);
    k_binB     <<<nb, dim3(BW), 0, stream>>>(binned, bucketCursor, sorted, rowrange, n, nb);
    k_l1_gather<<<gn,  blk, 0, stream>>>(rowrange, sorted, pk1, a_d1v, W1, b1, W2,
                                         as2, ad2, s1, pk2, n);
    k_l2_gather<<<gn,  blk, 0, stream>>>(rowrange, sorted, pk2, b2, s2, out, n);
    k_alpha    <<<gEt, blk, 0, stream>>>(ei, pk1, a_d1v, s1, pk2, s2,
                                         alpha1, alpha2, E, Et);
}

// Round 4
// 321.776 us; speedup vs baseline: 11.1146x; 1.3013x over previous
//
#include <hip/hip_runtime.h>
#include <hip/hip_fp16.h>
#include <math.h>

#define NEG_SLOPE 0.2f
#define BW 512          // bucket node width
#define BSH 9           // log2(BW)
#define CAP 18432       // per-bucket edge capacity (mean ~16.9K)
#define NB_MAX 256

__device__ __forceinline__ float lrelu(float v) {
    return v > 0.0f ? v : NEG_SLOPE * v;
}
__device__ __forceinline__ float pack2h(float a, float b) {
    __half2 h = __floats2half2_rn(a, b);
    return *reinterpret_cast<float*>(&h);
}
__device__ __forceinline__ float2 unpack2h(float f) {
    __half2 h = *reinterpret_cast<__half2*>(&f);
    return __half22float2(h);
}

// ---------------- K1: node projection. ga[i]={as01h,as23h,x0,x1};
// dpack[i] first half = {ad01h, ad23h} (rs written later by l1_gather).
__global__ __launch_bounds__(256) void k_l1_node(
    const float* __restrict__ x, const float* __restrict__ W1,
    const float* __restrict__ asw, const float* __restrict__ adw,
    float4* __restrict__ ga, float2* __restrict__ dpack2, int n)
{
    int i = blockIdx.x * blockDim.x + threadIdx.x;
    if (i >= n) return;
    float2 xv = ((const float2*)x)[i];
    float as[4] = {0.f, 0.f, 0.f, 0.f};
    float ad[4] = {0.f, 0.f, 0.f, 0.f};
    #pragma unroll
    for (int j = 0; j < 32; ++j) {
        float h = xv.x * W1[j] + xv.y * W1[32 + j];
        as[j >> 3] += h * asw[j];
        ad[j >> 3] += h * adw[j];
    }
    ga[i] = make_float4(pack2h(as[0], as[1]), pack2h(as[2], as[3]), xv.x, xv.y);
    dpack2[2 * i] = make_float2(pack2h(ad[0], ad[1]), pack2h(ad[2], ad[3]));
}

// ---------------- K0: zero bucket cursors
__global__ __launch_bounds__(256) void k_init(int* __restrict__ bucketCursor, int nb)
{
    int t = blockIdx.x * blockDim.x + threadIdx.x;
    if (t < nb) bucketCursor[t] = 0;
}

// ---------------- KA: LDS-binned bucket scatter (4096 edges/block).
__global__ __launch_bounds__(256) void k_binA(
    const int* __restrict__ ei, int* __restrict__ bucketCursor,
    unsigned int* __restrict__ binned, int E, int Et, int nb)
{
    __shared__ int cnt[NB_MAX], lscan[NB_MAX + 1], base[NB_MAX], lcur[NB_MAX];
    __shared__ unsigned int staging[4096];
    int t = threadIdx.x;
    int c0 = blockIdx.x * 4096;
    unsigned int ent[16];
    short bb[16];
    #pragma unroll
    for (int k = 0; k < 16; ++k) {
        int e = c0 + k * 256 + t;
        int s, d;
        if (e < E) { s = ei[e]; d = ei[E + e]; }
        else       { s = e - E; d = s; }
        bool valid = e < Et;
        bb[k] = valid ? (short)(d >> BSH) : (short)(-1);
        ent[k] = ((unsigned int)s << BSH) | (unsigned int)(d & (BW - 1));
    }
    if (t < nb) cnt[t] = 0;
    __syncthreads();
    #pragma unroll
    for (int k = 0; k < 16; ++k)
        if (bb[k] >= 0) atomicAdd(&cnt[bb[k]], 1);
    __syncthreads();
    if (t == 0) {
        int r = 0;
        for (int b = 0; b < nb; ++b) { lscan[b] = r; r += cnt[b]; }
        lscan[nb] = r;
    }
    __syncthreads();
    if (t < nb) {
        if (cnt[t] > 0) base[t] = atomicAdd(&bucketCursor[t], cnt[t]);
        lcur[t] = lscan[t];
    }
    __syncthreads();
    #pragma unroll
    for (int k = 0; k < 16; ++k)
        if (bb[k] >= 0) {
            int p = atomicAdd(&lcur[bb[k]], 1);
            staging[p] = ent[k];
        }
    __syncthreads();
    int total = lscan[nb];
    for (int j = t; j < total; j += 256) {
        int lo = 0, hi = nb - 1;
        while (lo < hi) {
            int mid = (lo + hi + 1) >> 1;
            if (lscan[mid] <= j) lo = mid; else hi = mid - 1;
        }
        binned[(size_t)lo * CAP + base[lo] + (j - lscan[lo])] = staging[j];
    }
}

// ---------------- KB: per-bucket counting sort -> CSR (no global atomics).
__global__ __launch_bounds__(512) void k_binB(
    const unsigned int* __restrict__ binned, const int* __restrict__ bucketCursor,
    int* __restrict__ sorted, int2* __restrict__ rowrange, int n, int nb)
{
    __shared__ int cnt[BW], cur[BW];
    int t = threadIdx.x;
    int b = blockIdx.x;
    int m = bucketCursor[b];
    size_t base = (size_t)b * CAP;
    int node0 = b << BSH;
    cnt[t] = 0;
    __syncthreads();
    for (int i = t; i < m; i += BW)
        atomicAdd(&cnt[binned[base + i] & (BW - 1)], 1);
    __syncthreads();
    int deg = cnt[t];
    for (int off = 1; off < BW; off <<= 1) {
        int v = (t >= off) ? cnt[t - off] : 0;
        __syncthreads();
        cnt[t] += v;
        __syncthreads();
    }
    int ex = cnt[t] - deg;
    cur[t] = ex;
    int node = node0 + t;
    if (node < n)
        rowrange[node] = make_int2((int)base + ex, (int)base + ex + deg);
    __syncthreads();
    for (int i = t; i < m; i += BW) {
        unsigned int en = binned[base + i];
        int dl = (int)(en & (BW - 1));
        int p = atomicAdd(&cur[dl], 1);
        sorted[base + p] = (int)(en >> BSH);
    }
}

// ---------------- K5: CSR layer-1 gather (1 thread/dst) + layer-2 node prep.
// Writes dpack rs half, pk2f[d]={as2,h20,h21,ad2}, a2s[d], d2[d]={ad2,_}.
__global__ __launch_bounds__(256) void k_l1_gather(
    const int2* __restrict__ rowrange, const int* __restrict__ sorted,
    const float4* __restrict__ ga, float2* __restrict__ dpack2,
    const float* __restrict__ W1, const float* __restrict__ b1,
    const float* __restrict__ W2,
    const float* __restrict__ asw2, const float* __restrict__ adw2,
    float4* __restrict__ pk2f, float* __restrict__ a2s,
    float2* __restrict__ d2, int n)
{
    int d = blockIdx.x * blockDim.x + threadIdx.x;
    if (d >= n) return;
    int2 rr = rowrange[d];
    int beg = rr.x, end = rr.y;
    float2 adp = dpack2[2 * d];
    float2 ad01 = unpack2h(adp.x), ad23 = unpack2h(adp.y);
    float see[4] = {0.f, 0.f, 0.f, 0.f};
    float sx0[4] = {0.f, 0.f, 0.f, 0.f};
    float sx1[4] = {0.f, 0.f, 0.f, 0.f};
    int s_next = (beg < end) ? sorted[beg] : 0;
    for (int i = beg; i < end; ++i) {
        int s = s_next;
        if (i + 1 < end) s_next = sorted[i + 1];
        float4 v = ga[s];
        float2 a01 = unpack2h(v.x), a23 = unpack2h(v.y);
        float e0 = __expf(lrelu(a01.x + ad01.x));
        float e1 = __expf(lrelu(a01.y + ad01.y));
        float e2 = __expf(lrelu(a23.x + ad23.x));
        float e3 = __expf(lrelu(a23.y + ad23.y));
        see[0] += e0; sx0[0] += e0 * v.z; sx1[0] += e0 * v.w;
        see[1] += e1; sx0[1] += e1 * v.z; sx1[1] += e1 * v.w;
        see[2] += e2; sx0[2] += e2 * v.z; sx1[2] += e2 * v.w;
        see[3] += e3; sx0[3] += e3 * v.z; sx1[3] += e3 * v.w;
    }
    float rs[4];
    #pragma unroll
    for (int h = 0; h < 4; ++h) rs[h] = 1.0f / (see[h] + 1e-16f);
    dpack2[2 * d + 1] = make_float2(pack2h(rs[0], rs[1]), pack2h(rs[2], rs[3]));
    float h20 = 0.f, h21 = 0.f;
    #pragma unroll
    for (int j = 0; j < 32; ++j) {
        int h = j >> 3;
        float num = W1[j] * sx0[h] + W1[32 + j] * sx1[h];
        float o = num * rs[h] + b1[j];
        float he = o > 0.f ? o : expm1f(o);
        h20 += he * W2[2 * j];
        h21 += he * W2[2 * j + 1];
    }
    float as2 = h20 * asw2[0] + h21 * asw2[1];
    float ad2 = h20 * adw2[0] + h21 * adw2[1];
    pk2f[d] = make_float4(as2, h20, h21, ad2);
    a2s[d] = as2;
    d2[d] = make_float2(ad2, 0.f);
}

// ---------------- K6: CSR layer-2 gather + output epilogue; writes rs2.
__global__ __launch_bounds__(256) void k_l2_gather(
    const int2* __restrict__ rowrange, const int* __restrict__ sorted,
    const float4* __restrict__ pk2f, const float* __restrict__ b2,
    float2* __restrict__ d2, float* __restrict__ out, int n)
{
    int d = blockIdx.x * blockDim.x + threadIdx.x;
    if (d >= n) return;
    int2 rr = rowrange[d];
    int beg = rr.x, end = rr.y;
    float ad2 = d2[d].x;
    float se = 0.f, a0 = 0.f, a1 = 0.f;
    int s_next = (beg < end) ? sorted[beg] : 0;
    for (int i = beg; i < end; ++i) {
        int s = s_next;
        if (i + 1 < end) s_next = sorted[i + 1];
        float4 p = pk2f[s];
        float ee = __expf(lrelu(p.x + ad2));
        se += ee;
        a0 += ee * p.y;
        a1 += ee * p.z;
    }
    float rs2 = 1.0f / (se + 1e-16f);
    d2[d].y = rs2;
    ((float2*)out)[d] = make_float2(a0 * rs2 + b2[0], a1 * rs2 + b2[1]);
}

// ---------------- K7a: COO alpha1 pass. Footprint: ga 8B/src + dpack 16B/dst
// = 2.4MB, L2-resident.
__global__ __launch_bounds__(256) void k_alpha1(
    const int* __restrict__ ei, const float2* __restrict__ ga2,
    const float4* __restrict__ dpack, float4* __restrict__ alpha1, int E, int Et)
{
    int e = blockIdx.x * blockDim.x + threadIdx.x;
    if (e >= Et) return;
    int s, d;
    if (e < E) { s = ei[e]; d = ei[E + e]; } else { s = e - E; d = s; }
    float2 g = ga2[2 * s];              // as01h, as23h
    float4 dp = dpack[d];               // ad01h, ad23h, rs01h, rs23h
    float2 a01 = unpack2h(g.x), a23 = unpack2h(g.y);
    float2 b01 = unpack2h(dp.x), b23 = unpack2h(dp.y);
    float2 r01 = unpack2h(dp.z), r23 = unpack2h(dp.w);
    float4 al;
    al.x = __expf(lrelu(a01.x + b01.x)) * r01.x;
    al.y = __expf(lrelu(a01.y + b01.y)) * r01.y;
    al.z = __expf(lrelu(a23.x + b23.x)) * r23.x;
    al.w = __expf(lrelu(a23.y + b23.y)) * r23.y;
    alpha1[e] = al;
}

// ---------------- K7b: COO alpha2 pass. Footprint: 4B/src + 8B/dst = 1.2MB.
__global__ __launch_bounds__(256) void k_alpha2(
    const int* __restrict__ ei, const float* __restrict__ a2s,
    const float2* __restrict__ d2, float* __restrict__ alpha2, int E, int Et)
{
    int e = blockIdx.x * blockDim.x + threadIdx.x;
    if (e >= Et) return;
    int s, d;
    if (e < E) { s = ei[e]; d = ei[E + e]; } else { s = e - E; d = s; }
    float2 dd = d2[d];
    alpha2[e] = __expf(lrelu(a2s[s] + dd.x)) * dd.y;
}

extern "C" void kernel_launch(void* const* d_in, const int* in_sizes, int n_in,
                              void* d_out, int out_size, void* d_ws, size_t ws_size,
                              hipStream_t stream)
{
    const float* x   = (const float*)d_in[0];
    const int*   ei  = (const int*)d_in[1];
    const float* W1  = (const float*)d_in[3];
    const float* as1 = (const float*)d_in[4];
    const float* ad1 = (const float*)d_in[5];
    const float* b1  = (const float*)d_in[6];
    const float* W2  = (const float*)d_in[7];
    const float* as2 = (const float*)d_in[8];
    const float* ad2 = (const float*)d_in[9];
    const float* b2  = (const float*)d_in[10];

    const int n  = in_sizes[0] / 2;   // 100000
    const int E  = in_sizes[1] / 2;   // 3200000
    const int Et = E + n;
    const int nb = (n + BW - 1) >> BSH;  // 196

    char* w = (char*)d_ws;
    float4* ga    = (float4*)w;  w += (size_t)n * sizeof(float4);
    float4* dpack = (float4*)w;  w += (size_t)n * sizeof(float4);
    float4* pk2f  = (float4*)w;  w += (size_t)n * sizeof(float4);
    float*  a2s   = (float*)w;   w += (size_t)n * sizeof(float);
    float2* d2    = (float2*)w;  w += (size_t)n * sizeof(float2);
    int2*   rowrange = (int2*)w; w += (size_t)n * sizeof(int2);
    int*    sorted   = (int*)w;  w += (size_t)nb * CAP * sizeof(int);
    int*    bucketCursor = (int*)w; w += (size_t)nb * sizeof(int);

    float*  out    = (float*)d_out;
    float4* alpha1 = (float4*)(out + (size_t)n * 2);
    float*  alpha2 = (float*)(alpha1 + (size_t)Et);
    // binned scratch lives in the alpha1 output region (14.5MB of 52.8MB);
    // consumed by k_binB, overwritten by k_alpha1 at the end.
    unsigned int* binned = (unsigned int*)alpha1;

    dim3 blk(256);
    int gn  = (n + 255) / 256;
    int gEt = (Et + 255) / 256;
    int gA  = (Et + 4095) / 4096;

    k_l1_node  <<<gn,  blk, 0, stream>>>(x, W1, as1, ad1, ga, (float2*)dpack, n);
    k_init     <<<1,   blk, 0, stream>>>(bucketCursor, nb);
    k_binA     <<<gA,  blk, 0, stream>>>(ei, bucketCursor, binned, E, Et, nb);
    k_binB     <<<nb, dim3(BW), 0, stream>>>(binned, bucketCursor, sorted, rowrange, n, nb);
    k_l1_gather<<<gn,  blk, 0, stream>>>(rowrange, sorted, ga, (float2*)dpack,
                                         W1, b1, W2, as2, ad2, pk2f, a2s, d2, n);
    k_l2_gather<<<gn,  blk, 0, stream>>>(rowrange, sorted, pk2f, b2, d2, out, n);
    k_alpha1   <<<gEt, blk, 0, stream>>>(ei, (const float2*)ga, dpack, alpha1, E, Et);
    k_alpha2   <<<gEt, blk, 0, stream>>>(ei, a2s, d2, alpha2, E, Et);
}

// Round 5
// 320.875 us; speedup vs baseline: 11.1458x; 1.0028x over previous
//
#include <hip/hip_runtime.h>
#include <hip/hip_fp16.h>
#include <math.h>

#define NEG_SLOPE 0.2f
#define BW 512          // bucket node width
#define BSH 9           // log2(BW)
#define CAP 18432       // per-bucket edge capacity (mean ~16.9K)
#define NB_MAX 256

typedef float f4v __attribute__((ext_vector_type(4)));

__device__ __forceinline__ float lrelu(float v) {
    return v > 0.0f ? v : NEG_SLOPE * v;
}
__device__ __forceinline__ float pack2h(float a, float b) {
    __half2 h = __floats2half2_rn(a, b);
    return *reinterpret_cast<float*>(&h);
}
__device__ __forceinline__ float2 unpack2h(float f) {
    __half2 h = *reinterpret_cast<__half2*>(&f);
    return __half22float2(h);
}
__device__ __forceinline__ void nt_store4(float4 v, float4* p) {
    f4v x = {v.x, v.y, v.z, v.w};
    __builtin_nontemporal_store(x, (f4v*)p);
}

// ---------------- K1: node projection.
// ga[i]={as01h,as23h,x0,x1}; as1h[i]={as01h,as23h};
// dpack[i] low half = {ad01h, ad23h} (rs half written by l1_gather).
__global__ __launch_bounds__(256) void k_l1_node(
    const float* __restrict__ x, const float* __restrict__ W1,
    const float* __restrict__ asw, const float* __restrict__ adw,
    float4* __restrict__ ga, float2* __restrict__ as1h,
    float2* __restrict__ dpack2, int n)
{
    int i = blockIdx.x * blockDim.x + threadIdx.x;
    if (i >= n) return;
    float2 xv = ((const float2*)x)[i];
    float as[4] = {0.f, 0.f, 0.f, 0.f};
    float ad[4] = {0.f, 0.f, 0.f, 0.f};
    #pragma unroll
    for (int j = 0; j < 32; ++j) {
        float h = xv.x * W1[j] + xv.y * W1[32 + j];
        as[j >> 3] += h * asw[j];
        ad[j >> 3] += h * adw[j];
    }
    float p01 = pack2h(as[0], as[1]), p23 = pack2h(as[2], as[3]);
    ga[i] = make_float4(p01, p23, xv.x, xv.y);
    as1h[i] = make_float2(p01, p23);
    dpack2[2 * i] = make_float2(pack2h(ad[0], ad[1]), pack2h(ad[2], ad[3]));
}

// ---------------- K0: zero bucket cursors
__global__ __launch_bounds__(256) void k_init(int* __restrict__ bucketCursor, int nb)
{
    int t = blockIdx.x * blockDim.x + threadIdx.x;
    if (t < nb) bucketCursor[t] = 0;
}

// ---------------- KA: LDS-binned bucket scatter (4096 edges/block).
__global__ __launch_bounds__(256) void k_binA(
    const int* __restrict__ ei, int* __restrict__ bucketCursor,
    unsigned int* __restrict__ binned, int E, int Et, int nb)
{
    __shared__ int cnt[NB_MAX], lscan[NB_MAX + 1], base[NB_MAX], lcur[NB_MAX];
    __shared__ unsigned int staging[4096];
    int t = threadIdx.x;
    int c0 = blockIdx.x * 4096;
    unsigned int ent[16];
    short bb[16];
    #pragma unroll
    for (int k = 0; k < 16; ++k) {
        int e = c0 + k * 256 + t;
        int s, d;
        if (e < E) {
            s = __builtin_nontemporal_load(&ei[e]);
            d = __builtin_nontemporal_load(&ei[E + e]);
        } else { s = e - E; d = s; }
        bool valid = e < Et;
        bb[k] = valid ? (short)(d >> BSH) : (short)(-1);
        ent[k] = ((unsigned int)s << BSH) | (unsigned int)(d & (BW - 1));
    }
    if (t < nb) cnt[t] = 0;
    __syncthreads();
    #pragma unroll
    for (int k = 0; k < 16; ++k)
        if (bb[k] >= 0) atomicAdd(&cnt[bb[k]], 1);
    __syncthreads();
    if (t == 0) {
        int r = 0;
        for (int b = 0; b < nb; ++b) { lscan[b] = r; r += cnt[b]; }
        lscan[nb] = r;
    }
    __syncthreads();
    if (t < nb) {
        if (cnt[t] > 0) base[t] = atomicAdd(&bucketCursor[t], cnt[t]);
        lcur[t] = lscan[t];
    }
    __syncthreads();
    #pragma unroll
    for (int k = 0; k < 16; ++k)
        if (bb[k] >= 0) {
            int p = atomicAdd(&lcur[bb[k]], 1);
            staging[p] = ent[k];
        }
    __syncthreads();
    int total = lscan[nb];
    for (int j = t; j < total; j += 256) {
        int lo = 0, hi = nb - 1;
        while (lo < hi) {
            int mid = (lo + hi + 1) >> 1;
            if (lscan[mid] <= j) lo = mid; else hi = mid - 1;
        }
        __builtin_nontemporal_store(staging[j],
            &binned[(size_t)lo * CAP + base[lo] + (j - lscan[lo])]);
    }
}

// ---------------- KB: per-bucket counting sort -> CSR (1024 threads).
__global__ __launch_bounds__(1024) void k_binB(
    const unsigned int* __restrict__ binned, const int* __restrict__ bucketCursor,
    int* __restrict__ sorted, int2* __restrict__ rowrange, int n, int nb)
{
    __shared__ int cnt[BW], cur[BW];
    int t = threadIdx.x;
    int b = blockIdx.x;
    int m = bucketCursor[b];
    size_t base = (size_t)b * CAP;
    int node0 = b << BSH;
    if (t < BW) cnt[t] = 0;
    __syncthreads();
    for (int i = t; i < m; i += 1024)
        atomicAdd(&cnt[binned[base + i] & (BW - 1)], 1);
    __syncthreads();
    int deg = (t < BW) ? cnt[t] : 0;
    for (int off = 1; off < BW; off <<= 1) {
        int v = (t >= off && t < BW) ? cnt[t - off] : 0;
        __syncthreads();
        if (t < BW) cnt[t] += v;
        __syncthreads();
    }
    if (t < BW) {
        int ex = cnt[t] - deg;
        cur[t] = ex;
        int node = node0 + t;
        if (node < n)
            rowrange[node] = make_int2((int)base + ex, (int)base + ex + deg);
    }
    __syncthreads();
    for (int i = t; i < m; i += 1024) {
        unsigned int en = binned[base + i];
        int dl = (int)(en & (BW - 1));
        int p = atomicAdd(&cur[dl], 1);
        sorted[base + p] = (int)(en >> BSH);
    }
}

// ---------------- K5: CSR layer-1 gather (1 thread/dst, unroll 4) + L2 prep.
__global__ __launch_bounds__(128) void k_l1_gather(
    const int2* __restrict__ rowrange, const int* __restrict__ sorted,
    const float4* __restrict__ ga, float2* __restrict__ dpack2,
    const float* __restrict__ W1, const float* __restrict__ b1,
    const float* __restrict__ W2,
    const float* __restrict__ asw2, const float* __restrict__ adw2,
    float4* __restrict__ pk2f, float* __restrict__ a2s,
    float2* __restrict__ d2, int n)
{
    int d = blockIdx.x * blockDim.x + threadIdx.x;
    if (d >= n) return;
    int2 rr = rowrange[d];
    int beg = rr.x, end = rr.y;
    float2 adp = dpack2[2 * d];
    float2 ad01 = unpack2h(adp.x), ad23 = unpack2h(adp.y);
    float see[4] = {0.f, 0.f, 0.f, 0.f};
    float sx0[4] = {0.f, 0.f, 0.f, 0.f};
    float sx1[4] = {0.f, 0.f, 0.f, 0.f};
    int i = beg;
    for (; i + 4 <= end; i += 4) {
        int s0 = sorted[i], s1 = sorted[i + 1], s2 = sorted[i + 2], s3 = sorted[i + 3];
        float4 v0 = ga[s0], v1 = ga[s1], v2 = ga[s2], v3 = ga[s3];
        #pragma unroll
        for (int k = 0; k < 4; ++k) {
            float4 v = (k == 0) ? v0 : (k == 1) ? v1 : (k == 2) ? v2 : v3;
            float2 a01 = unpack2h(v.x), a23 = unpack2h(v.y);
            float e0 = __expf(lrelu(a01.x + ad01.x));
            float e1 = __expf(lrelu(a01.y + ad01.y));
            float e2 = __expf(lrelu(a23.x + ad23.x));
            float e3 = __expf(lrelu(a23.y + ad23.y));
            see[0] += e0; sx0[0] += e0 * v.z; sx1[0] += e0 * v.w;
            see[1] += e1; sx0[1] += e1 * v.z; sx1[1] += e1 * v.w;
            see[2] += e2; sx0[2] += e2 * v.z; sx1[2] += e2 * v.w;
            see[3] += e3; sx0[3] += e3 * v.z; sx1[3] += e3 * v.w;
        }
    }
    for (; i < end; ++i) {
        float4 v = ga[sorted[i]];
        float2 a01 = unpack2h(v.x), a23 = unpack2h(v.y);
        float e0 = __expf(lrelu(a01.x + ad01.x));
        float e1 = __expf(lrelu(a01.y + ad01.y));
        float e2 = __expf(lrelu(a23.x + ad23.x));
        float e3 = __expf(lrelu(a23.y + ad23.y));
        see[0] += e0; sx0[0] += e0 * v.z; sx1[0] += e0 * v.w;
        see[1] += e1; sx0[1] += e1 * v.z; sx1[1] += e1 * v.w;
        see[2] += e2; sx0[2] += e2 * v.z; sx1[2] += e2 * v.w;
        see[3] += e3; sx0[3] += e3 * v.z; sx1[3] += e3 * v.w;
    }
    float rs[4];
    #pragma unroll
    for (int h = 0; h < 4; ++h) rs[h] = 1.0f / (see[h] + 1e-16f);
    dpack2[2 * d + 1] = make_float2(pack2h(rs[0], rs[1]), pack2h(rs[2], rs[3]));
    float h20 = 0.f, h21 = 0.f;
    #pragma unroll
    for (int j = 0; j < 32; ++j) {
        int h = j >> 3;
        float num = W1[j] * sx0[h] + W1[32 + j] * sx1[h];
        float o = num * rs[h] + b1[j];
        float he = o > 0.f ? o : expm1f(o);
        h20 += he * W2[2 * j];
        h21 += he * W2[2 * j + 1];
    }
    float as2 = h20 * asw2[0] + h21 * asw2[1];
    float ad2 = h20 * adw2[0] + h21 * adw2[1];
    pk2f[d] = make_float4(as2, h20, h21, ad2);
    a2s[d] = as2;
    d2[d] = make_float2(ad2, 0.f);
}

// ---------------- K6: CSR layer-2 gather (unroll 4) + output epilogue.
__global__ __launch_bounds__(128) void k_l2_gather(
    const int2* __restrict__ rowrange, const int* __restrict__ sorted,
    const float4* __restrict__ pk2f, const float* __restrict__ b2,
    float2* __restrict__ d2, float* __restrict__ out, int n)
{
    int d = blockIdx.x * blockDim.x + threadIdx.x;
    if (d >= n) return;
    int2 rr = rowrange[d];
    int beg = rr.x, end = rr.y;
    float ad2 = d2[d].x;
    float se = 0.f, a0 = 0.f, a1 = 0.f;
    int i = beg;
    for (; i + 4 <= end; i += 4) {
        int s0 = sorted[i], s1 = sorted[i + 1], s2 = sorted[i + 2], s3 = sorted[i + 3];
        float4 p0 = pk2f[s0], p1 = pk2f[s1], p2 = pk2f[s2], p3 = pk2f[s3];
        float e0 = __expf(lrelu(p0.x + ad2));
        float e1 = __expf(lrelu(p1.x + ad2));
        float e2 = __expf(lrelu(p2.x + ad2));
        float e3 = __expf(lrelu(p3.x + ad2));
        se += e0 + e1 + e2 + e3;
        a0 += e0 * p0.y + e1 * p1.y + e2 * p2.y + e3 * p3.y;
        a1 += e0 * p0.z + e1 * p1.z + e2 * p2.z + e3 * p3.z;
    }
    for (; i < end; ++i) {
        float4 p = pk2f[sorted[i]];
        float ee = __expf(lrelu(p.x + ad2));
        se += ee; a0 += ee * p.y; a1 += ee * p.z;
    }
    float rs2 = 1.0f / (se + 1e-16f);
    d2[d].y = rs2;
    ((float2*)out)[d] = make_float2(a0 * rs2 + b2[0], a1 * rs2 + b2[1]);
}

// ---------------- K7a: COO alpha1 pass (src 8B as1h + dst 16B dpack = 2.4MB).
__global__ __launch_bounds__(256) void k_alpha1(
    const int* __restrict__ ei, const float2* __restrict__ as1h,
    const float4* __restrict__ dpack, float4* __restrict__ alpha1, int E, int Et)
{
    int e = blockIdx.x * blockDim.x + threadIdx.x;
    if (e >= Et) return;
    int s, d;
    if (e < E) {
        s = __builtin_nontemporal_load(&ei[e]);
        d = __builtin_nontemporal_load(&ei[E + e]);
    } else { s = e - E; d = s; }
    float2 g = as1h[s];
    float4 dp = dpack[d];
    float2 a01 = unpack2h(g.x), a23 = unpack2h(g.y);
    float2 b01 = unpack2h(dp.x), b23 = unpack2h(dp.y);
    float2 r01 = unpack2h(dp.z), r23 = unpack2h(dp.w);
    float4 al;
    al.x = __expf(lrelu(a01.x + b01.x)) * r01.x;
    al.y = __expf(lrelu(a01.y + b01.y)) * r01.y;
    al.z = __expf(lrelu(a23.x + b23.x)) * r23.x;
    al.w = __expf(lrelu(a23.y + b23.y)) * r23.y;
    nt_store4(al, &alpha1[e]);
}

// ---------------- K7b: COO alpha2 pass (src 4B + dst 8B = 1.2MB).
__global__ __launch_bounds__(256) void k_alpha2(
    const int* __restrict__ ei, const float* __restrict__ a2s,
    const float2* __restrict__ d2, float* __restrict__ alpha2, int E, int Et)
{
    int e = blockIdx.x * blockDim.x + threadIdx.x;
    if (e >= Et) return;
    int s, d;
    if (e < E) {
        s = __builtin_nontemporal_load(&ei[e]);
        d = __builtin_nontemporal_load(&ei[E + e]);
    } else { s = e - E; d = s; }
    float2 dd = d2[d];
    __builtin_nontemporal_store(__expf(lrelu(a2s[s] + dd.x)) * dd.y, &alpha2[e]);
}

extern "C" void kernel_launch(void* const* d_in, const int* in_sizes, int n_in,
                              void* d_out, int out_size, void* d_ws, size_t ws_size,
                              hipStream_t stream)
{
    const float* x   = (const float*)d_in[0];
    const int*   ei  = (const int*)d_in[1];
    const float* W1  = (const float*)d_in[3];
    const float* as1 = (const float*)d_in[4];
    const float* ad1 = (const float*)d_in[5];
    const float* b1  = (const float*)d_in[6];
    const float* W2  = (const float*)d_in[7];
    const float* as2 = (const float*)d_in[8];
    const float* ad2 = (const float*)d_in[9];
    const float* b2  = (const float*)d_in[10];

    const int n  = in_sizes[0] / 2;   // 100000
    const int E  = in_sizes[1] / 2;   // 3200000
    const int Et = E + n;
    const int nb = (n + BW - 1) >> BSH;  // 196

    char* w = (char*)d_ws;
    float4* ga    = (float4*)w;  w += (size_t)n * sizeof(float4);
    float2* as1h  = (float2*)w;  w += (size_t)n * sizeof(float2);
    float4* dpack = (float4*)w;  w += (size_t)n * sizeof(float4);
    float4* pk2f  = (float4*)w;  w += (size_t)n * sizeof(float4);
    float*  a2s   = (float*)w;   w += (size_t)n * sizeof(float);
    float2* d2    = (float2*)w;  w += (size_t)n * sizeof(float2);
    int2*   rowrange = (int2*)w; w += (size_t)n * sizeof(int2);
    int*    sorted   = (int*)w;  w += (size_t)nb * CAP * sizeof(int);
    int*    bucketCursor = (int*)w; w += (size_t)nb * sizeof(int);

    float*  out    = (float*)d_out;
    float4* alpha1 = (float4*)(out + (size_t)n * 2);
    float*  alpha2 = (float*)(alpha1 + (size_t)Et);
    // binned scratch lives in the alpha1 output region, overwritten by k_alpha1.
    unsigned int* binned = (unsigned int*)alpha1;

    dim3 blk(256);
    int gn  = (n + 255) / 256;
    int gn128 = (n + 127) / 128;
    int gEt = (Et + 255) / 256;
    int gA  = (Et + 4095) / 4096;

    k_l1_node  <<<gn,  blk, 0, stream>>>(x, W1, as1, ad1, ga, as1h, (float2*)dpack, n);
    k_init     <<<1,   blk, 0, stream>>>(bucketCursor, nb);
    k_binA     <<<gA,  blk, 0, stream>>>(ei, bucketCursor, binned, E, Et, nb);
    k_binB     <<<nb, dim3(1024), 0, stream>>>(binned, bucketCursor, sorted, rowrange, n, nb);
    k_l1_gather<<<gn128, dim3(128), 0, stream>>>(rowrange, sorted, ga, (float2*)dpack,
                                         W1, b1, W2, as2, ad2, pk2f, a2s, d2, n);
    k_l2_gather<<<gn128, dim3(128), 0, stream>>>(rowrange, sorted, pk2f, b2, d2, out, n);
    k_alpha1   <<<gEt, blk, 0, stream>>>(ei, as1h, dpack, alpha1, E, Et);
    k_alpha2   <<<gEt, blk, 0, stream>>>(ei, a2s, d2, alpha2, E, Et);
}

// Round 6
// 293.368 us; speedup vs baseline: 12.1909x; 1.0938x over previous
//
#include <hip/hip_runtime.h>
#include <hip/hip_fp16.h>
#include <math.h>

#define NEG_SLOPE 0.2f
#define BW 512          // bucket node width
#define BSH 9           // log2(BW)
#define CAP 18432       // per-bucket edge capacity (mean ~16.9K)
#define NB_MAX 256

typedef float f4v __attribute__((ext_vector_type(4)));
typedef float f2v __attribute__((ext_vector_type(2)));
typedef int   i2v __attribute__((ext_vector_type(2)));

__device__ __forceinline__ float lrelu(float v) {
    return v > 0.0f ? v : NEG_SLOPE * v;
}
__device__ __forceinline__ float pack2h(float a, float b) {
    __half2 h = __floats2half2_rn(a, b);
    return *reinterpret_cast<float*>(&h);
}
__device__ __forceinline__ float2 unpack2h(float f) {
    __half2 h = *reinterpret_cast<__half2*>(&f);
    return __half22float2(h);
}
__device__ __forceinline__ void nt_store4(float4 v, float4* p) {
    f4v x = {v.x, v.y, v.z, v.w};
    __builtin_nontemporal_store(x, (f4v*)p);
}
__device__ __forceinline__ void nt_store2(float2 v, float2* p) {
    f2v x = {v.x, v.y};
    __builtin_nontemporal_store(x, (f2v*)p);
}

// ---------------- K1: node projection (+ zero bucket cursors).
// ga[i]={as01h,as23h,x0,x1}; spack[i]={as01h,as23h, as2(later), 0};
// dpack[i] low float2 = {ad01h, ad23h} (rs half written by l1_gather).
__global__ __launch_bounds__(256) void k_l1_node(
    const float* __restrict__ x, const float* __restrict__ W1,
    const float* __restrict__ asw, const float* __restrict__ adw,
    float4* __restrict__ ga, float4* __restrict__ spack,
    float2* __restrict__ dpack2, int* __restrict__ bucketCursor,
    int nb, int n)
{
    int i = blockIdx.x * blockDim.x + threadIdx.x;
    if (i < nb) bucketCursor[i] = 0;
    if (i >= n) return;
    float2 xv = ((const float2*)x)[i];
    float as[4] = {0.f, 0.f, 0.f, 0.f};
    float ad[4] = {0.f, 0.f, 0.f, 0.f};
    #pragma unroll
    for (int j = 0; j < 32; ++j) {
        float h = xv.x * W1[j] + xv.y * W1[32 + j];
        as[j >> 3] += h * asw[j];
        ad[j >> 3] += h * adw[j];
    }
    float p01 = pack2h(as[0], as[1]), p23 = pack2h(as[2], as[3]);
    ga[i] = make_float4(p01, p23, xv.x, xv.y);
    spack[i] = make_float4(p01, p23, 0.f, 0.f);
    dpack2[2 * i] = make_float2(pack2h(ad[0], ad[1]), pack2h(ad[2], ad[3]));
}

// ---------------- KA: LDS-binned bucket scatter (4096 edges/block).
// Per staged slot also records its bucket (sbk) -> no binary search on drain.
__global__ __launch_bounds__(256) void k_binA(
    const int* __restrict__ ei, int* __restrict__ bucketCursor,
    unsigned int* __restrict__ binned, int E, int Et, int nb)
{
    __shared__ int cnt[NB_MAX], lscan[NB_MAX], base[NB_MAX], lcur[NB_MAX];
    __shared__ unsigned int staging[4096];
    __shared__ short sbk[4096];
    int t = threadIdx.x;
    int c0 = blockIdx.x * 4096;
    unsigned int ent[16];
    short bb[16];
    #pragma unroll
    for (int k = 0; k < 16; ++k) {
        int e = c0 + k * 256 + t;
        int s, d;
        if (e < E) {
            s = __builtin_nontemporal_load(&ei[e]);
            d = __builtin_nontemporal_load(&ei[E + e]);
        } else { s = e - E; d = s; }
        bool valid = e < Et;
        bb[k] = valid ? (short)(d >> BSH) : (short)(-1);
        ent[k] = ((unsigned int)s << BSH) | (unsigned int)(d & (BW - 1));
    }
    cnt[t] = 0;
    __syncthreads();
    #pragma unroll
    for (int k = 0; k < 16; ++k)
        if (bb[k] >= 0) atomicAdd(&cnt[bb[k]], 1);
    __syncthreads();
    int c = cnt[t];
    lscan[t] = c;
    __syncthreads();
    // parallel inclusive scan over 256 entries
    for (int off = 1; off < 256; off <<= 1) {
        int v = (t >= off) ? lscan[t - off] : 0;
        __syncthreads();
        lscan[t] += v;
        __syncthreads();
    }
    int tot = lscan[255];
    int ex = lscan[t] - c;
    __syncthreads();
    lscan[t] = ex;          // chunk-local exclusive start of bucket t
    lcur[t] = ex;
    if (t < nb && c > 0) base[t] = atomicAdd(&bucketCursor[t], c);
    __syncthreads();
    #pragma unroll
    for (int k = 0; k < 16; ++k)
        if (bb[k] >= 0) {
            int p = atomicAdd(&lcur[bb[k]], 1);
            staging[p] = ent[k];
            sbk[p] = bb[k];
        }
    __syncthreads();
    for (int j = t; j < tot; j += 256) {
        int lo = sbk[j];
        __builtin_nontemporal_store(staging[j],
            &binned[(size_t)lo * CAP + base[lo] + (j - lscan[lo])]);
    }
}

// ---------------- KB: per-bucket counting sort -> CSR (1024 threads).
__global__ __launch_bounds__(1024) void k_binB(
    const unsigned int* __restrict__ binned, const int* __restrict__ bucketCursor,
    int* __restrict__ sorted, int2* __restrict__ rowrange, int n, int nb)
{
    __shared__ int cnt[BW], cur[BW];
    int t = threadIdx.x;
    int b = blockIdx.x;
    int m = bucketCursor[b];
    size_t base = (size_t)b * CAP;
    int node0 = b << BSH;
    if (t < BW) cnt[t] = 0;
    __syncthreads();
    for (int i = t; i < m; i += 1024)
        atomicAdd(&cnt[binned[base + i] & (BW - 1)], 1);
    __syncthreads();
    int deg = (t < BW) ? cnt[t] : 0;
    for (int off = 1; off < BW; off <<= 1) {
        int v = (t >= off && t < BW) ? cnt[t - off] : 0;
        __syncthreads();
        if (t < BW) cnt[t] += v;
        __syncthreads();
    }
    if (t < BW) {
        int ex = cnt[t] - deg;
        cur[t] = ex;
        int node = node0 + t;
        if (node < n)
            rowrange[node] = make_int2((int)base + ex, (int)base + ex + deg);
    }
    __syncthreads();
    for (int i = t; i < m; i += 1024) {
        unsigned int en = binned[base + i];
        int dl = (int)(en & (BW - 1));
        int p = atomicAdd(&cur[dl], 1);
        sorted[base + p] = (int)(en >> BSH);
    }
}

// ---------------- K5: CSR layer-1 gather, 2 lanes per dst row + L2 prep.
__global__ __launch_bounds__(256) void k_l1_gather(
    const int2* __restrict__ rowrange, const int* __restrict__ sorted,
    const float4* __restrict__ ga, float2* __restrict__ dpack2,
    const float* __restrict__ W1, const float* __restrict__ b1,
    const float* __restrict__ W2,
    const float* __restrict__ asw2, const float* __restrict__ adw2,
    float4* __restrict__ pk2f, float4* __restrict__ spack,
    __half* __restrict__ dpk2h, int n)
{
    int t = blockIdx.x * blockDim.x + threadIdx.x;
    int d = t >> 1, half = t & 1;
    if (d >= n) return;
    int2 rr = rowrange[d];
    int beg = rr.x, end = rr.y;
    float2 adp = dpack2[2 * d];
    float2 ad01 = unpack2h(adp.x), ad23 = unpack2h(adp.y);
    float see[4] = {0.f, 0.f, 0.f, 0.f};
    float sx0[4] = {0.f, 0.f, 0.f, 0.f};
    float sx1[4] = {0.f, 0.f, 0.f, 0.f};
    int i = beg + half;
    for (; i + 2 < end; i += 4) {
        int s0 = sorted[i], s1 = sorted[i + 2];
        float4 v0 = ga[s0], v1 = ga[s1];
        #pragma unroll
        for (int k = 0; k < 2; ++k) {
            float4 v = k ? v1 : v0;
            float2 a01 = unpack2h(v.x), a23 = unpack2h(v.y);
            float e0 = __expf(lrelu(a01.x + ad01.x));
            float e1 = __expf(lrelu(a01.y + ad01.y));
            float e2 = __expf(lrelu(a23.x + ad23.x));
            float e3 = __expf(lrelu(a23.y + ad23.y));
            see[0] += e0; sx0[0] += e0 * v.z; sx1[0] += e0 * v.w;
            see[1] += e1; sx0[1] += e1 * v.z; sx1[1] += e1 * v.w;
            see[2] += e2; sx0[2] += e2 * v.z; sx1[2] += e2 * v.w;
            see[3] += e3; sx0[3] += e3 * v.z; sx1[3] += e3 * v.w;
        }
    }
    for (; i < end; i += 2) {
        float4 v = ga[sorted[i]];
        float2 a01 = unpack2h(v.x), a23 = unpack2h(v.y);
        float e0 = __expf(lrelu(a01.x + ad01.x));
        float e1 = __expf(lrelu(a01.y + ad01.y));
        float e2 = __expf(lrelu(a23.x + ad23.x));
        float e3 = __expf(lrelu(a23.y + ad23.y));
        see[0] += e0; sx0[0] += e0 * v.z; sx1[0] += e0 * v.w;
        see[1] += e1; sx0[1] += e1 * v.z; sx1[1] += e1 * v.w;
        see[2] += e2; sx0[2] += e2 * v.z; sx1[2] += e2 * v.w;
        see[3] += e3; sx0[3] += e3 * v.z; sx1[3] += e3 * v.w;
    }
    // combine lane pairs
    #pragma unroll
    for (int h = 0; h < 4; ++h) {
        see[h] += __shfl_xor(see[h], 1);
        sx0[h] += __shfl_xor(sx0[h], 1);
        sx1[h] += __shfl_xor(sx1[h], 1);
    }
    if (half) return;
    float rs[4];
    #pragma unroll
    for (int h = 0; h < 4; ++h) rs[h] = 1.0f / (see[h] + 1e-16f);
    dpack2[2 * d + 1] = make_float2(pack2h(rs[0], rs[1]), pack2h(rs[2], rs[3]));
    float h20 = 0.f, h21 = 0.f;
    #pragma unroll
    for (int j = 0; j < 32; ++j) {
        int h = j >> 3;
        float num = W1[j] * sx0[h] + W1[32 + j] * sx1[h];
        float o = num * rs[h] + b1[j];
        float he = o > 0.f ? o : expm1f(o);
        h20 += he * W2[2 * j];
        h21 += he * W2[2 * j + 1];
    }
    float as2 = h20 * asw2[0] + h21 * asw2[1];
    float ad2 = h20 * adw2[0] + h21 * adw2[1];
    pk2f[d] = make_float4(as2, h20, h21, ad2);
    ((float*)&spack[d])[2] = as2;        // spack.z
    dpk2h[2 * d] = __float2half(ad2);    // low half of packed {ad2h, rs2h}
}

// ---------------- K6: CSR layer-2 gather, 2 lanes per dst row + epilogue.
__global__ __launch_bounds__(256) void k_l2_gather(
    const int2* __restrict__ rowrange, const int* __restrict__ sorted,
    const float4* __restrict__ pk2f, const float* __restrict__ b2,
    __half* __restrict__ dpk2h, float* __restrict__ out, int n)
{
    int t = blockIdx.x * blockDim.x + threadIdx.x;
    int d = t >> 1, half = t & 1;
    if (d >= n) return;
    int2 rr = rowrange[d];
    int beg = rr.x, end = rr.y;
    float ad2 = pk2f[d].w;
    float se = 0.f, a0 = 0.f, a1 = 0.f;
    int i = beg + half;
    for (; i + 2 < end; i += 4) {
        int s0 = sorted[i], s1 = sorted[i + 2];
        float4 p0 = pk2f[s0], p1 = pk2f[s1];
        float e0 = __expf(lrelu(p0.x + ad2));
        float e1 = __expf(lrelu(p1.x + ad2));
        se += e0 + e1;
        a0 += e0 * p0.y + e1 * p1.y;
        a1 += e0 * p0.z + e1 * p1.z;
    }
    for (; i < end; i += 2) {
        float4 p = pk2f[sorted[i]];
        float ee = __expf(lrelu(p.x + ad2));
        se += ee; a0 += ee * p.y; a1 += ee * p.z;
    }
    se += __shfl_xor(se, 1);
    a0 += __shfl_xor(a0, 1);
    a1 += __shfl_xor(a1, 1);
    if (half) return;
    float rs2 = 1.0f / (se + 1e-16f);
    dpk2h[2 * d + 1] = __float2half(rs2);  // high half of {ad2h, rs2h}
    ((float2*)out)[d] = make_float2(a0 * rs2 + b2[0], a1 * rs2 + b2[1]);
}

// ---------------- K7: merged COO alpha pass, 2 edges/thread.
// src: spack[s]={as01h,as23h,as2,_}; dst: dpack[d] 16B + dpk2hf[d] 4B.
__global__ __launch_bounds__(256) void k_alpha(
    const int* __restrict__ ei, const float4* __restrict__ spack,
    const float4* __restrict__ dpack, const float* __restrict__ dpk2hf,
    float4* __restrict__ alpha1, float2* __restrict__ alpha2_2, int E, int Et)
{
    int p = blockIdx.x * blockDim.x + threadIdx.x;
    int e0 = p * 2;
    if (e0 >= Et) return;
    int s0, d0, s1, d1;
    if (e0 < E) {   // E is even: pairs never straddle the self-loop boundary
        i2v ss = __builtin_nontemporal_load(&((const i2v*)ei)[p]);
        i2v dd = __builtin_nontemporal_load((const i2v*)(ei + E) + (p - E / 2) + E / 2 - E / 2 + (p - 0) - p + p); // simplified below
        dd = __builtin_nontemporal_load((const i2v*)(ei + E) + p);
        s0 = ss.x; s1 = ss.y; d0 = dd.x; d1 = dd.y;
    } else {
        s0 = e0 - E; d0 = s0; s1 = s0 + 1; d1 = s1;
    }
    float4 sp0 = spack[s0], sp1 = spack[s1];
    float4 dp0 = dpack[d0], dp1 = dpack[d1];
    float  dh0 = dpk2hf[d0], dh1 = dpk2hf[d1];

    float2 a01, a23, b01, b23, r01, r23, ar;
    float4 al;
    // edge 0
    a01 = unpack2h(sp0.x); a23 = unpack2h(sp0.y);
    b01 = unpack2h(dp0.x); b23 = unpack2h(dp0.y);
    r01 = unpack2h(dp0.z); r23 = unpack2h(dp0.w);
    al.x = __expf(lrelu(a01.x + b01.x)) * r01.x;
    al.y = __expf(lrelu(a01.y + b01.y)) * r01.y;
    al.z = __expf(lrelu(a23.x + b23.x)) * r23.x;
    al.w = __expf(lrelu(a23.y + b23.y)) * r23.y;
    nt_store4(al, &alpha1[e0]);
    ar = unpack2h(dh0);
    float o20 = __expf(lrelu(sp0.z + ar.x)) * ar.y;
    // edge 1
    a01 = unpack2h(sp1.x); a23 = unpack2h(sp1.y);
    b01 = unpack2h(dp1.x); b23 = unpack2h(dp1.y);
    r01 = unpack2h(dp1.z); r23 = unpack2h(dp1.w);
    al.x = __expf(lrelu(a01.x + b01.x)) * r01.x;
    al.y = __expf(lrelu(a01.y + b01.y)) * r01.y;
    al.z = __expf(lrelu(a23.x + b23.x)) * r23.x;
    al.w = __expf(lrelu(a23.y + b23.y)) * r23.y;
    nt_store4(al, &alpha1[e0 + 1]);
    ar = unpack2h(dh1);
    float o21 = __expf(lrelu(sp1.z + ar.x)) * ar.y;
    nt_store2(make_float2(o20, o21), &alpha2_2[p]);
}

extern "C" void kernel_launch(void* const* d_in, const int* in_sizes, int n_in,
                              void* d_out, int out_size, void* d_ws, size_t ws_size,
                              hipStream_t stream)
{
    const float* x   = (const float*)d_in[0];
    const int*   ei  = (const int*)d_in[1];
    const float* W1  = (const float*)d_in[3];
    const float* as1 = (const float*)d_in[4];
    const float* ad1 = (const float*)d_in[5];
    const float* b1  = (const float*)d_in[6];
    const float* W2  = (const float*)d_in[7];
    const float* as2 = (const float*)d_in[8];
    const float* ad2 = (const float*)d_in[9];
    const float* b2  = (const float*)d_in[10];

    const int n  = in_sizes[0] / 2;   // 100000
    const int E  = in_sizes[1] / 2;   // 3200000 (even)
    const int Et = E + n;             // even
    const int nb = (n + BW - 1) >> BSH;  // 196

    char* w = (char*)d_ws;
    float4* ga    = (float4*)w;  w += (size_t)n * sizeof(float4);
    float4* spack = (float4*)w;  w += (size_t)n * sizeof(float4);
    float4* dpack = (float4*)w;  w += (size_t)n * sizeof(float4);
    float4* pk2f  = (float4*)w;  w += (size_t)n * sizeof(float4);
    float*  dpk2hf= (float*)w;   w += (size_t)n * sizeof(float);
    int2*   rowrange = (int2*)w; w += (size_t)n * sizeof(int2);
    int*    sorted   = (int*)w;  w += (size_t)nb * CAP * sizeof(int);
    int*    bucketCursor = (int*)w; w += (size_t)nb * sizeof(int);

    float*  out    = (float*)d_out;
    float4* alpha1 = (float4*)(out + (size_t)n * 2);
    float2* alpha2_2 = (float2*)(alpha1 + (size_t)Et);
    // binned scratch lives in the alpha1 output region, overwritten by k_alpha.
    unsigned int* binned = (unsigned int*)alpha1;

    dim3 blk(256);
    int gn   = (n + 255) / 256;
    int gn2  = (2 * n + 255) / 256;
    int gA   = (Et + 4095) / 4096;
    int gP   = (Et / 2 + 255) / 256;

    k_l1_node  <<<gn,  blk, 0, stream>>>(x, W1, as1, ad1, ga, spack,
                                         (float2*)dpack, bucketCursor, nb, n);
    k_binA     <<<gA,  blk, 0, stream>>>(ei, bucketCursor, binned, E, Et, nb);
    k_binB     <<<nb, dim3(1024), 0, stream>>>(binned, bucketCursor, sorted, rowrange, n, nb);
    k_l1_gather<<<gn2, blk, 0, stream>>>(rowrange, sorted, ga, (float2*)dpack,
                                         W1, b1, W2, as2, ad2, pk2f, spack,
                                         (__half*)dpk2hf, n);
    k_l2_gather<<<gn2, blk, 0, stream>>>(rowrange, sorted, pk2f, b2,
                                         (__half*)dpk2hf, out, n);
    k_alpha    <<<gP,  blk, 0, stream>>>(ei, spack, dpack, dpk2hf,
                                         alpha1, alpha2_2, E, Et);
}